// Round 16
// baseline (1906.328 us; speedup 1.0000x reference)
//
#include <hip/hip_runtime.h>

#define AS1 __attribute__((address_space(1)))
#define AS3 __attribute__((address_space(3)))

typedef __bf16 bf16;
typedef unsigned char u8;
typedef unsigned int u32;
typedef unsigned long long u64;
typedef __bf16 bf16x8 __attribute__((ext_vector_type(8)));
typedef __bf16 bf16x4v __attribute__((ext_vector_type(4)));
typedef float  f32x4  __attribute__((ext_vector_type(4)));
typedef float  f32x16 __attribute__((ext_vector_type(16)));
typedef long   i64x2  __attribute__((ext_vector_type(2)));

#define MFMA16(a,b,c) __builtin_amdgcn_mfma_f32_16x16x32_bf16((a),(b),(c),0,0,0)
#define MFMA32(a,b,c) __builtin_amdgcn_mfma_f32_32x32x16_bf16((a),(b),(c),0,0,0)
#define MFMA32F8(a,b,c) __builtin_amdgcn_mfma_f32_32x32x16_fp8_fp8((a),(b),(c),0,0,0)
#define BARX() asm volatile("s_waitcnt lgkmcnt(0)\ns_barrier" ::: "memory")
#define VMW(n) asm volatile("s_waitcnt vmcnt(" #n ")" ::: "memory")

static __device__ __forceinline__ void gll16(const bf16* src, bf16* lds) {
  __builtin_amdgcn_global_load_lds((const AS1 void*)src, (AS3 void*)lds, 16, 0, 0);
}
static __device__ __forceinline__ void gll16b(const u8* src, u8* lds) {
  __builtin_amdgcn_global_load_lds((const AS1 void*)src, (AS3 void*)lds, 16, 0, 0);
}

// ---------------- Kernel 0: weights fp32 -> bf16 (all 4 in one launch) ----------------
__global__ void convw_k(const float* __restrict__ s0, const float* __restrict__ s1,
                        const float* __restrict__ s2, const float* __restrict__ s3,
                        bf16* __restrict__ d) {
  const int which = blockIdx.x >> 8;
  const float* s = (which == 0) ? s0 : (which == 1) ? s1 : (which == 2) ? s2 : s3;
  bf16* dd = d + ((size_t)which << 18);
  int i = ((blockIdx.x & 255) * 256 + threadIdx.x) * 4;
  float4 v = *(const float4*)(s + i);
  bf16x4v o;
  o[0] = (bf16)v.x; o[1] = (bf16)v.y; o[2] = (bf16)v.z; o[3] = (bf16)v.w;
  *(bf16x4v*)(dd + i) = o;
}

// ------------- Kernel 1: transpose+convert feat [B,C,4096] -> [B,4096,C] bf16 -------------
__global__ void tconv_k(const float* __restrict__ f0, const float* __restrict__ f1,
                        bf16* __restrict__ xq, bf16* __restrict__ xkv) {
  const int z = blockIdx.z;
  const int b = z & 7;
  const float* src = (z < 8) ? f0 : f1;
  bf16* dst = (z < 8) ? xq : xkv;
  const int n0 = blockIdx.x * 32, c0 = blockIdx.y * 32;
  __shared__ float tile[32][33];
  const int tx = threadIdx.x, ty = threadIdx.y;
  const size_t base = (size_t)b * 512 * 4096;
#pragma unroll
  for (int i = 0; i < 4; i++) {
    int c = ty + i * 8;
    tile[c][tx] = src[base + (size_t)(c0 + c) * 4096 + n0 + tx];
  }
  __syncthreads();
  const size_t ob = (size_t)b * 4096 * 512;
#pragma unroll
  for (int i = 0; i < 4; i++) {
    int n = ty + i * 8;
    dst[ob + (size_t)(n0 + n) * 512 + c0 + tx] = (bf16)tile[tx][n];
  }
}

// ------------- Kernel 2: generic GEMM  out[r,co] = sum_k A[r,k]*W[co,k] + bias[co] -------------
// MODE 0: out bf16 [B,4096,512] plain                  (Q)
// MODE 4: fused K+V: W = concat(Wk,Wv) [1024][512]; co<512 -> K plain bf16 (outB);
//         co>=512 -> V fp8 image (outF cast to u8), bias-V via `resid`.
//         V image: [B][tile=kv>>5][co*32 + ((kv>>3)&1)*16 + (kv>>4)*8 + (kv&7)]
// MODE 2: out fp32 transposed [B,512,4096] + residual feat0  (final)
template<int MODE>
__global__ __launch_bounds__(256) void gemm_k(const bf16* __restrict__ A, const bf16* __restrict__ W,
                                              const float* __restrict__ bias, bf16* __restrict__ outB,
                                              float* __restrict__ outF, const float* __restrict__ resid) {
  const int b = blockIdx.y;
  const int CTB = (MODE == 4) ? 3 : 2;
  const int rt = blockIdx.x >> CTB, ct = blockIdx.x & ((1 << CTB) - 1);
  const int r0 = rt * 128, c0 = ct * 128;
  const int t = threadIdx.x, w = t >> 6, l = t & 63;
  __shared__ alignas(16) bf16 As[128 * 32];
  __shared__ alignas(16) bf16 Bs[128 * 32];
  f32x4 acc[4][4];
  const f32x4 fzero = {0.f, 0.f, 0.f, 0.f};
#pragma unroll
  for (int m = 0; m < 4; m++)
#pragma unroll
    for (int n = 0; n < 4; n++) acc[m][n] = fzero;
  const bf16* Ab = A + (size_t)b * 4096 * 512 + (size_t)r0 * 512;
  const int wr = (w >> 1) * 64, wc = (w & 1) * 64;
  for (int kk = 0; kk < 16; kk++) {
    const int k0 = kk * 32;
#pragma unroll
    for (int h = 0; h < 2; h++) {
      const int rowbase = w * 32 + h * 16;
      const int row = rowbase + (l >> 2);
      const int cl = (l & 3) ^ ((row >> 1) & 3);
      gll16(Ab + (size_t)row * 512 + k0 + cl * 8, As + rowbase * 32);
      gll16(W + (size_t)(c0 + row) * 512 + k0 + cl * 8, Bs + rowbase * 32);
    }
    __syncthreads();
    bf16x8 af[4], bfr[4];
#pragma unroll
    for (int m = 0; m < 4; m++) {
      const int row = wr + m * 16 + (l & 15);
      af[m] = *(const bf16x8*)(As + row * 32 + (((l >> 4) ^ ((row >> 1) & 3)) << 3));
    }
#pragma unroll
    for (int n = 0; n < 4; n++) {
      const int row = wc + n * 16 + (l & 15);
      bfr[n] = *(const bf16x8*)(Bs + row * 32 + (((l >> 4) ^ ((row >> 1) & 3)) << 3));
    }
#pragma unroll
    for (int m = 0; m < 4; m++)
#pragma unroll
      for (int n = 0; n < 4; n++)
        acc[m][n] = MFMA16(af[m], bfr[n], acc[m][n]);
    __syncthreads();
  }
#pragma unroll
  for (int n = 0; n < 4; n++) {
    const int co = c0 + wc + n * 16 + (l & 15);
    const float bv = (MODE == 4 && co >= 512) ? resid[co - 512] : bias[co];
#pragma unroll
    for (int m = 0; m < 4; m++) {
      const int rb = r0 + wr + m * 16 + ((l >> 4) << 2);
      if constexpr (MODE == 0) {
#pragma unroll
        for (int i = 0; i < 4; i++)
          outB[(size_t)b * 4096 * 512 + (size_t)(rb + i) * 512 + co] = (bf16)(acc[m][n][i] + bv);
      } else if constexpr (MODE == 4) {
        if (co < 512) {
#pragma unroll
          for (int i = 0; i < 4; i++)
            outB[(size_t)b * 4096 * 512 + (size_t)(rb + i) * 512 + co] = (bf16)(acc[m][n][i] + bv);
        } else {
          const int cop = co - 512;
          int pw = 0;
          pw = __builtin_amdgcn_cvt_pk_fp8_f32(acc[m][n][0] + bv, acc[m][n][1] + bv, pw, false);
          pw = __builtin_amdgcn_cvt_pk_fp8_f32(acc[m][n][2] + bv, acc[m][n][3] + bv, pw, true);
          const int kvin = rb & 31;
          u8* ov = (u8*)outF;
          const size_t o = ((size_t)b * 128 + (rb >> 5)) * 16384 + (size_t)cop * 32 +
                           ((kvin >> 3) & 1) * 16 + (kvin >> 4) * 8 + (kvin & 7);
          *(int*)(ov + o) = pw;
        }
      } else {
        const size_t o = ((size_t)b * 512 + co) * 4096 + rb;
        float4 rv = *(const float4*)(resid + o);
        float4 ov;
        ov.x = acc[m][n][0] + bv + rv.x;
        ov.y = acc[m][n][1] + bv + rv.y;
        ov.z = acc[m][n][2] + bv + rv.z;
        ov.w = acc[m][n][3] + bv + rv.w;
        *(float4*)(outF + o) = ov;
      }
    }
  }
}

// ------------- Kernel 3: flash cross-attention, pair-split-C, 32x32 MFMA, f32 exchange ---------
// 8 waves = 4 pairs; pair p owns q-rows [n0+32p,+32); wave h of a pair owns C/co half h.
// QK: S^T[key][q] = mfma32(K-frag, Q-frag) over C-half; partner partials exchanged in F32 LDS.
// PV: D[co][q] = mfma32(V-frag, P-frag) — q = lane&31 so softmax state is lane-scalar.
// LDS: K ring-2 64K + V ring-2 32K + Sx f32 32K = 128 KiB. Stage issued AFTER B1 (ring-2 safe:
// every reader of tile t finishes before B1(t+1)); VMW(0) at top has ~3/4 iter of latency cover.
__global__ __launch_bounds__(512, 2) void flash_k(const bf16* __restrict__ Q, const bf16* __restrict__ K,
                                                  const u8* __restrict__ Vt, bf16* __restrict__ ctx) {
  __shared__ alignas(16) bf16  Ks[2][32 * 512];   // 64 KB ring-2
  __shared__ alignas(16) u8    Vs[2][16384];      // 32 KB ring-2
  __shared__ alignas(16) float Sx[8][1024];       // 32 KB f32 exchange: [wave][kc*256 + l*4]
  const int flat = blockIdx.x;
  const int fs = (flat & 7) * 32 + (flat >> 3);   // XCD swizzle (256 = 8*32, bijective)
  const int b = fs >> 5, n0 = (fs & 31) * 128;
  const int tid = threadIdx.x, w = tid >> 6, l = tid & 63;
  const int h = w & 1, p = w >> 1;
  const int q31 = l & 31, hw = l >> 5;
  const int kswz = l & 7;                         // key&7 (key = l&31)

  // Q fragments (B-operand of QK32): lane holds Q[n0+32p+q31][h*256 + ki*16 + 8*hw .. +7]
  bf16x8 qf[16];
  {
    const bf16* Qb = Q + ((size_t)b * 4096 + n0 + p * 32 + q31) * 512 + h * 256 + hw * 8;
#pragma unroll
    for (int ki = 0; ki < 16; ki++) qf[ki] = *(const bf16x8*)(Qb + ki * 16);
  }
  f32x16 acc[8];
#pragma unroll
  for (int ct = 0; ct < 8; ct++)
#pragma unroll
    for (int i = 0; i < 16; i++) acc[ct][i] = 0.f;
  float mrow = -1e30f, lrow = 0.f;   // per-lane; q = l&31 (lanes l, l^32 share mrow exactly)

  // staging offsets (tile-invariant). K: LDS row linear, source chunk ^ (row&7).
  int koff[4];
#pragma unroll
  for (int j = 0; j < 4; j++) {
    const int row = w * 4 + j;
    koff[j] = row * 512 + ((l ^ (row & 7)) << 3);
  }
  const int voff0 = w * 2048 + l * 16;            // V: fully linear (image pre-arranged)
  const bf16* Kg = K + (size_t)b * 4096 * 512;
  const u8* Vg = Vt + (size_t)b * 128 * 16384;
  VMW(0);  // drain qf loads

  // prologue: stage tile 0 into slot 0 (4 K ops + 2 V ops per wave)
#pragma unroll
  for (int j = 0; j < 4; j++) gll16(Kg + koff[j], &Ks[0][0] + (w * 4 + j) * 512);
#pragma unroll
  for (int j = 0; j < 2; j++) gll16b(Vg + voff0 + j * 1024, &Vs[0][0] + voff0 + j * 1024);

#pragma unroll 1
  for (int t = 0; t < 128; ++t) {
    VMW(0);     // tile t resident (staged ~3/4 iteration ago)
    BARX();     // B1: tile t visible to all waves; all waves done reading slot (t+1)&1
    // ---- stage tile t+1 into slot (t+1)&1 (ring-2 safe: issued after B1) ----
    if (t < 127) {
      const bf16* ks = Kg + (size_t)(t + 1) * 16384;
      const u8* vs = Vg + (size_t)(t + 1) * 16384;
      bf16* kd = &Ks[(t + 1) & 1][0];
      u8* vd = &Vs[(t + 1) & 1][0];
#pragma unroll
      for (int j = 0; j < 4; j++) gll16(ks + koff[j], kd + (w * 4 + j) * 512);
#pragma unroll
      for (int j = 0; j < 2; j++) gll16b(vs + voff0 + j * 1024, vd + voff0 + j * 1024);
    }

    // ---- QK32 over my C-half: key row = l&31, q col = l&31 ----
    const bf16* kb0 = &Ks[t & 1][0] + (size_t)q31 * 512;
    f32x16 sp;
#pragma unroll
    for (int i = 0; i < 16; i++) sp[i] = 0.f;
#pragma unroll
    for (int ki = 0; ki < 16; ki++) {
      const int cidx = 32 * h + 2 * ki + hw;
      bf16x8 af = *(const bf16x8*)(kb0 + ((cidx ^ kswz) << 3));
      sp = MFMA32(af, qf[ki], sp);
    }
    // ---- write own partial (f32) to exchange; [kc*1024B + l*16B] linear, full-rate ----
    float* sxw = &Sx[w][0];
#pragma unroll
    for (int kc = 0; kc < 4; kc++) {
      f32x4 v4 = {sp[4 * kc], sp[4 * kc + 1], sp[4 * kc + 2], sp[4 * kc + 3]};
      *(f32x4*)(sxw + kc * 256 + (l << 2)) = v4;
    }
    BARX();     // B2: partials visible to partner; QK reads of Ks[t&1] done

    // ---- assemble full S = own + partner (both f32) ----
    const float* sxp = &Sx[w ^ 1][0];
    float e[16];
#pragma unroll
    for (int kc = 0; kc < 4; kc++) {
      const f32x4 pr = *(const f32x4*)(sxp + kc * 256 + (l << 2));
      e[4 * kc + 0] = sp[4 * kc + 0] + pr[0];
      e[4 * kc + 1] = sp[4 * kc + 1] + pr[1];
      e[4 * kc + 2] = sp[4 * kc + 2] + pr[2];
      e[4 * kc + 3] = sp[4 * kc + 3] + pr[3];
    }
    // ---- online softmax, defer-max THR=5 (P <= e^5 < fp8 max 448); q lane-local ----
    float pmax = e[0];
#pragma unroll
    for (int i = 1; i < 16; i++) pmax = fmaxf(pmax, e[i]);
    if (!__all(pmax <= mrow + 5.0f)) {
      const float rmax = fmaxf(pmax, __shfl_xor(pmax, 32));
      const float mnew = fmaxf(mrow, rmax);
      const float scl = __expf(mrow - mnew);
      mrow = mnew;
      lrow *= scl;
#pragma unroll
      for (int ct = 0; ct < 8; ct++) acc[ct] *= scl;
    }
    float rs = 0.f;
#pragma unroll
    for (int i = 0; i < 16; i++) { e[i] = __expf(e[i] - mrow); rs += e[i]; }
    lrow += rs;

    // ---- pack P->fp8 (key(r) = (r&3)+8*(r>>2)+4*hw), swap halves via shfl_xor(32) ----
    int w0 = 0, w1 = 0, w2 = 0, w3 = 0;
    w0 = __builtin_amdgcn_cvt_pk_fp8_f32(e[0], e[1], w0, false);
    w0 = __builtin_amdgcn_cvt_pk_fp8_f32(e[2], e[3], w0, true);
    w1 = __builtin_amdgcn_cvt_pk_fp8_f32(e[4], e[5], w1, false);
    w1 = __builtin_amdgcn_cvt_pk_fp8_f32(e[6], e[7], w1, true);
    w2 = __builtin_amdgcn_cvt_pk_fp8_f32(e[8], e[9], w2, false);
    w2 = __builtin_amdgcn_cvt_pk_fp8_f32(e[10], e[11], w2, true);
    w3 = __builtin_amdgcn_cvt_pk_fp8_f32(e[12], e[13], w3, false);
    w3 = __builtin_amdgcn_cvt_pk_fp8_f32(e[14], e[15], w3, true);
    const int sw0 = __shfl_xor(w0, 32);
    const int sw1 = __shfl_xor(w1, 32);
    const int sw2 = __shfl_xor(w2, 32);
    const int sw3 = __shfl_xor(w3, 32);
    const u32 f1lo = (u32)(hw ? sw1 : w0), f1hi = (u32)(hw ? w1 : sw0);
    const u32 f2lo = (u32)(hw ? sw3 : w2), f2hi = (u32)(hw ? w3 : sw2);
    const long pf1 = (long)(((u64)f1hi << 32) | f1lo);   // P[q][keys hw*8..+7]
    const long pf2 = (long)(((u64)f2hi << 32) | f2lo);   // P[q][keys 16+hw*8..+7]

    // ---- PV: D[co][q] += V^T x P ; V row co = h*256+ct*32+(l&31), 16B chunk hw ----
    const u8* vb = &Vs[t & 1][0] + (size_t)(h * 256 + q31) * 32 + hw * 16;
    __builtin_amdgcn_s_setprio(1);
#pragma unroll
    for (int ct = 0; ct < 8; ct++) {
      const i64x2 vv = *(const i64x2*)(vb + ct * 1024);
      acc[ct] = MFMA32F8(vv[0], pf1, acc[ct]);
      acc[ct] = MFMA32F8(vv[1], pf2, acc[ct]);
    }
    __builtin_amdgcn_s_setprio(0);
  }

  // ---- epilogue: denom reduce (1 shfl), scale, store; co rows = (r&3)+8(r>>2)+4hw ----
  float lr = lrow + __shfl_xor(lrow, 32);
  const float inv = 0.04419417382415922f / lr;
  const size_t nb = ((size_t)b * 4096 + n0 + p * 32 + q31) * 512;
#pragma unroll
  for (int ct = 0; ct < 8; ct++) {
#pragma unroll
    for (int a = 0; a < 4; a++) {
      const int co = h * 256 + ct * 32 + 8 * a + 4 * hw;
      bf16x4v pk;
#pragma unroll
      for (int j = 0; j < 4; j++) pk[j] = (bf16)(acc[ct][4 * a + j] * inv);
      *(bf16x4v*)(ctx + nb + co) = pk;
    }
  }
}

extern "C" void kernel_launch(void* const* d_in, const int* in_sizes, int n_in,
                              void* d_out, int out_size, void* d_ws, size_t ws_size,
                              hipStream_t stream) {
  const float* feat0 = (const float*)d_in[0];
  const float* feat1 = (const float*)d_in[1];
  const float* Wq = (const float*)d_in[2];
  const float* bq = (const float*)d_in[3];
  const float* Wk = (const float*)d_in[4];
  const float* bk = (const float*)d_in[5];
  const float* Wv = (const float*)d_in[6];
  const float* bv = (const float*)d_in[7];
  const float* Wo = (const float*)d_in[8];
  const float* bo = (const float*)d_in[9];
  float* out = (float*)d_out;

  char* ws = (char*)d_ws;
  bf16* Wqb = (bf16*)(ws);
  bf16* Wkb = (bf16*)(ws + (1 << 19));        // Wkb and Wvb contiguous -> concat [1024][512]
  bf16* Wob = (bf16*)(ws + 3 * (size_t)(1 << 19));
  const size_t TEN = (size_t)8 * 4096 * 512 * 2;  // 33.55 MB per bf16 tensor
  char* p = ws + 4 * (size_t)(1 << 19);
  bf16* Xq  = (bf16*)(p);
  bf16* Xkv = (bf16*)(p + TEN);
  bf16* Qb  = (bf16*)(p + 2 * TEN);
  bf16* Kb  = (bf16*)(p + 3 * TEN);
  bf16* Vtb = (bf16*)(p + 4 * TEN);   // fp8 image (16 MB)
  bf16* ctx = Xq;  // Xq dead after Q projection

  convw_k<<<1024, 256, 0, stream>>>(Wq, Wk, Wv, Wo, Wqb);
  tconv_k<<<dim3(128, 16, 16), dim3(32, 8), 0, stream>>>(feat0, feat1, Xq, Xkv);
  gemm_k<0><<<dim3(128, 8), 256, 0, stream>>>(Xq,  Wqb, bq, Qb, nullptr, nullptr);
  gemm_k<4><<<dim3(256, 8), 256, 0, stream>>>(Xkv, Wkb, bk, Kb, (float*)Vtb, bv);
  flash_k<<<dim3(256), dim3(512), 0, stream>>>(Qb, Kb, (const u8*)Vtb, ctx);
  gemm_k<2><<<dim3(128, 8), 256, 0, stream>>>(ctx, Wob, bo, nullptr, out, feat0);
}

// Round 17
// 469.278 us; speedup vs baseline: 4.0623x; 4.0623x over previous
//
#include <hip/hip_runtime.h>

#define AS1 __attribute__((address_space(1)))
#define AS3 __attribute__((address_space(3)))

typedef __bf16 bf16;
typedef unsigned char u8;
typedef unsigned int u32;
typedef __bf16 bf16x8 __attribute__((ext_vector_type(8)));
typedef __bf16 bf16x4v __attribute__((ext_vector_type(4)));
typedef float  f32x4  __attribute__((ext_vector_type(4)));
typedef long   i64x2  __attribute__((ext_vector_type(2)));

#define MFMA16(a,b,c) __builtin_amdgcn_mfma_f32_16x16x32_bf16((a),(b),(c),0,0,0)
#define MFMAF8(a,b,c) __builtin_amdgcn_mfma_f32_16x16x32_fp8_fp8((a),(b),(c),0,0,0)
#define BARX() asm volatile("s_waitcnt lgkmcnt(0)\ns_barrier" ::: "memory")
#define VMW(n) asm volatile("s_waitcnt vmcnt(" #n ")" ::: "memory")

static __device__ __forceinline__ void gll16(const bf16* src, bf16* lds) {
  __builtin_amdgcn_global_load_lds((const AS1 void*)src, (AS3 void*)lds, 16, 0, 0);
}
static __device__ __forceinline__ void gll16b(const u8* src, u8* lds) {
  __builtin_amdgcn_global_load_lds((const AS1 void*)src, (AS3 void*)lds, 16, 0, 0);
}

// ---------------- Kernel 0: weights fp32 -> bf16 (all 4 in one launch) ----------------
__global__ void convw_k(const float* __restrict__ s0, const float* __restrict__ s1,
                        const float* __restrict__ s2, const float* __restrict__ s3,
                        bf16* __restrict__ d) {
  const int which = blockIdx.x >> 8;
  const float* s = (which == 0) ? s0 : (which == 1) ? s1 : (which == 2) ? s2 : s3;
  bf16* dd = d + ((size_t)which << 18);
  int i = ((blockIdx.x & 255) * 256 + threadIdx.x) * 4;
  float4 v = *(const float4*)(s + i);
  bf16x4v o;
  o[0] = (bf16)v.x; o[1] = (bf16)v.y; o[2] = (bf16)v.z; o[3] = (bf16)v.w;
  *(bf16x4v*)(dd + i) = o;
}

// ------------- Kernel 1: transpose+convert feat [B,C,4096] -> [B,4096,C] bf16 -------------
__global__ void tconv_k(const float* __restrict__ f0, const float* __restrict__ f1,
                        bf16* __restrict__ xq, bf16* __restrict__ xkv) {
  const int z = blockIdx.z;
  const int b = z & 7;
  const float* src = (z < 8) ? f0 : f1;
  bf16* dst = (z < 8) ? xq : xkv;
  const int n0 = blockIdx.x * 32, c0 = blockIdx.y * 32;
  __shared__ float tile[32][33];
  const int tx = threadIdx.x, ty = threadIdx.y;
  const size_t base = (size_t)b * 512 * 4096;
#pragma unroll
  for (int i = 0; i < 4; i++) {
    int c = ty + i * 8;
    tile[c][tx] = src[base + (size_t)(c0 + c) * 4096 + n0 + tx];
  }
  __syncthreads();
  const size_t ob = (size_t)b * 4096 * 512;
#pragma unroll
  for (int i = 0; i < 4; i++) {
    int n = ty + i * 8;
    dst[ob + (size_t)(n0 + n) * 512 + c0 + tx] = (bf16)tile[tx][n];
  }
}

// ------------- Kernel 2: generic GEMM  out[r,co] = sum_k A[r,k]*W[co,k] + bias[co] -------------
// MODE 0: out bf16 [B,4096,512] plain                  (Q)
// MODE 4: fused K+V: W = concat(Wk,Wv) [1024][512]; co<512 -> K plain bf16 (outB);
//         co>=512 -> V fp8 paired image (outF cast to u8), bias-V passed via `resid`.
// MODE 2: out fp32 transposed [B,512,4096] + residual feat0  (final)
// V paired image: [B][tile=kv>>5][g=(kv&31)>>3][(co>>5)*256 + (co&15)*16 + ((co>>4)&1)*8 + (kv&7)]
template<int MODE>
__global__ __launch_bounds__(256) void gemm_k(const bf16* __restrict__ A, const bf16* __restrict__ W,
                                              const float* __restrict__ bias, bf16* __restrict__ outB,
                                              float* __restrict__ outF, const float* __restrict__ resid) {
  const int b = blockIdx.y;
  const int CTB = (MODE == 4) ? 3 : 2;
  const int rt = blockIdx.x >> CTB, ct = blockIdx.x & ((1 << CTB) - 1);
  const int r0 = rt * 128, c0 = ct * 128;
  const int t = threadIdx.x, w = t >> 6, l = t & 63;
  __shared__ alignas(16) bf16 As[128 * 32];
  __shared__ alignas(16) bf16 Bs[128 * 32];
  f32x4 acc[4][4];
  const f32x4 fzero = {0.f, 0.f, 0.f, 0.f};
#pragma unroll
  for (int m = 0; m < 4; m++)
#pragma unroll
    for (int n = 0; n < 4; n++) acc[m][n] = fzero;
  const bf16* Ab = A + (size_t)b * 4096 * 512 + (size_t)r0 * 512;
  const int wr = (w >> 1) * 64, wc = (w & 1) * 64;
  for (int kk = 0; kk < 16; kk++) {
    const int k0 = kk * 32;
#pragma unroll
    for (int h = 0; h < 2; h++) {
      const int rowbase = w * 32 + h * 16;
      const int row = rowbase + (l >> 2);
      const int cl = (l & 3) ^ ((row >> 1) & 3);
      gll16(Ab + (size_t)row * 512 + k0 + cl * 8, As + rowbase * 32);
      gll16(W + (size_t)(c0 + row) * 512 + k0 + cl * 8, Bs + rowbase * 32);
    }
    __syncthreads();
    bf16x8 af[4], bfr[4];
#pragma unroll
    for (int m = 0; m < 4; m++) {
      const int row = wr + m * 16 + (l & 15);
      af[m] = *(const bf16x8*)(As + row * 32 + (((l >> 4) ^ ((row >> 1) & 3)) << 3));
    }
#pragma unroll
    for (int n = 0; n < 4; n++) {
      const int row = wc + n * 16 + (l & 15);
      bfr[n] = *(const bf16x8*)(Bs + row * 32 + (((l >> 4) ^ ((row >> 1) & 3)) << 3));
    }
#pragma unroll
    for (int m = 0; m < 4; m++)
#pragma unroll
      for (int n = 0; n < 4; n++)
        acc[m][n] = MFMA16(af[m], bfr[n], acc[m][n]);
    __syncthreads();
  }
#pragma unroll
  for (int n = 0; n < 4; n++) {
    const int co = c0 + wc + n * 16 + (l & 15);
    const float bv = (MODE == 4 && co >= 512) ? resid[co - 512] : bias[co];
#pragma unroll
    for (int m = 0; m < 4; m++) {
      const int rb = r0 + wr + m * 16 + ((l >> 4) << 2);
      if constexpr (MODE == 0) {
#pragma unroll
        for (int i = 0; i < 4; i++)
          outB[(size_t)b * 4096 * 512 + (size_t)(rb + i) * 512 + co] = (bf16)(acc[m][n][i] + bv);
      } else if constexpr (MODE == 4) {
        if (co < 512) {
#pragma unroll
          for (int i = 0; i < 4; i++)
            outB[(size_t)b * 4096 * 512 + (size_t)(rb + i) * 512 + co] = (bf16)(acc[m][n][i] + bv);
        } else {
          const int cop = co - 512;
          int pw = 0;
          pw = __builtin_amdgcn_cvt_pk_fp8_f32(acc[m][n][0] + bv, acc[m][n][1] + bv, pw, false);
          pw = __builtin_amdgcn_cvt_pk_fp8_f32(acc[m][n][2] + bv, acc[m][n][3] + bv, pw, true);
          const int kvin = rb & 31;
          u8* ov = (u8*)outF;
          const size_t o = (((size_t)b * 128 + (rb >> 5)) * 4 + (kvin >> 3)) * 4096 +
                           (cop >> 5) * 256 + (cop & 15) * 16 + ((cop >> 4) & 1) * 8 + (rb & 7);
          *(int*)(ov + o) = pw;
        }
      } else {
        const size_t o = ((size_t)b * 512 + co) * 4096 + rb;
        float4 rv = *(const float4*)(resid + o);
        float4 ov;
        ov.x = acc[m][n][0] + bv + rv.x;
        ov.y = acc[m][n][1] + bv + rv.y;
        ov.z = acc[m][n][2] + bv + rv.z;
        ov.w = acc[m][n][3] + bv + rv.w;
        *(float4*)(outF + o) = ov;
      }
    }
  }
}

// ------------- Kernel 3: flash cross-attention (R12 champion + shuffle-free softmax path) ------
// 8 waves x 16 q-rows = 128 q/block. Q [B,4096,512] bf16; K [B,4096,512] bf16 (source-swizzled
// staging); V fp8 paired image. Ring-3 K (96KB) + ring-3 V (48KB), single barrier, VMW(6).
__global__ __launch_bounds__(512, 2) void flash_k(const bf16* __restrict__ Q, const bf16* __restrict__ K,
                                                  const u8* __restrict__ Vt, bf16* __restrict__ ctx) {
  __shared__ alignas(16) bf16 Ks[3][32 * 512];   // 96 KB ring-3
  __shared__ alignas(16) u8   Vs[3][16384];      // 48 KB ring-3
  const int flat = blockIdx.x;
  const int fs = (flat & 7) * 32 + (flat >> 3);  // XCD swizzle (256 = 8*32, bijective)
  const int b = fs >> 5, n0 = (fs & 31) * 128;
  const int tid = threadIdx.x, w = tid >> 6, l = tid & 63;
  const int g = l >> 4, r16 = l & 15;
  const int kswz = r16 & 7;

  // Q fragments (B-operand): lane holds Q[n0+w*16+r16][f*32 + g*8 .. +7]
  bf16x8 qf[16];
  {
    const bf16* Qb = Q + ((size_t)b * 4096 + n0 + w * 16 + r16) * 512 + g * 8;
#pragma unroll
    for (int f = 0; f < 16; f++) qf[f] = *(const bf16x8*)(Qb + f * 32);
  }
  f32x4 acc[32];
  const f32x4 fz = {0.f, 0.f, 0.f, 0.f};
#pragma unroll
  for (int f = 0; f < 32; f++) acc[f] = fz;
  float mrow = -1e30f, lrow = 0.f;   // lrow = per-lane PARTIAL denominator (reduced in epilogue)

  // staging offsets (tile-invariant). K: LDS row linear, source chunk ^ (row&7).
  int koff[4];
#pragma unroll
  for (int j = 0; j < 4; j++) {
    const int row = w * 4 + j;
    koff[j] = row * 512 + ((l ^ (row & 7)) << 3);
  }
  const int voff0 = w * 2048 + l * 16;           // V: fully linear (image pre-arranged)
  const bf16* Kg = K + (size_t)b * 4096 * 512;
  const u8* Vg = Vt + (size_t)b * 128 * 16384;
  VMW(0);  // drain qf loads so vmcnt counting below is exact

  // prologue: stage tile 0 into slot 0 (4 K ops + 2 V ops per wave)
#pragma unroll
  for (int j = 0; j < 4; j++) gll16(Kg + koff[j], &Ks[0][0] + (w * 4 + j) * 512);
#pragma unroll
  for (int j = 0; j < 2; j++) gll16b(Vg + voff0 + j * 1024, &Vs[0][0] + voff0 + j * 1024);

  int cur = 0, nxt = 1;
#pragma unroll 1
  for (int t = 0; t < 128; ++t) {
    // ---- stage tile t+1 into slot nxt (safe: slowest reader is tile t-1 in slot prv) ----
    if (t < 127) {
      const bf16* ks = Kg + (size_t)(t + 1) * 16384;
      const u8* vs = Vg + (size_t)(t + 1) * 16384;
      bf16* kd = &Ks[nxt][0];
      u8* vd = &Vs[nxt][0];
#pragma unroll
      for (int j = 0; j < 4; j++) gll16(ks + koff[j], kd + (w * 4 + j) * 512);
#pragma unroll
      for (int j = 0; j < 2; j++) gll16b(vs + voff0 + j * 1024, vd + voff0 + j * 1024);
      VMW(6);   // tile t's 6 ops complete; t+1's 6 stay in flight
    } else {
      VMW(0);
    }
    BARX();     // single barrier: all waves' tile-t data visible

    // ---- QK^T: S^T[key][q], 4 independent MFMA chains ----
    const bf16* kb0 = &Ks[cur][0] + r16 * 512;
    f32x4 sa = fz, sb = fz, sc2 = fz, sd = fz;
#pragma unroll
    for (int f2 = 0; f2 < 16; f2 += 2) {
      const int c0i = ((((f2 << 2) + g) ^ kswz) << 3);
      const int c1i = (((((f2 + 1) << 2) + g) ^ kswz) << 3);
      bf16x8 k0 = *(const bf16x8*)(kb0 + c0i);
      bf16x8 k1 = *(const bf16x8*)(kb0 + 16 * 512 + c0i);
      bf16x8 k2 = *(const bf16x8*)(kb0 + c1i);
      bf16x8 k3 = *(const bf16x8*)(kb0 + 16 * 512 + c1i);
      sa = MFMA16(k0, qf[f2], sa);
      sb = MFMA16(k1, qf[f2], sb);
      sc2 = MFMA16(k2, qf[f2 + 1], sc2);
      sd = MFMA16(k3, qf[f2 + 1], sd);
    }
    const f32x4 s0 = sa + sc2, s1 = sb + sd;   // lane(q=r16): keys 4g+i / 16+4g+i

    // ---- online softmax, defer-max THR=5; shuffle-free fast path ----
    float pmax = fmaxf(fmaxf(fmaxf(s0[0], s0[1]), fmaxf(s0[2], s0[3])),
                       fmaxf(fmaxf(s1[0], s1[1]), fmaxf(s1[2], s1[3])));
    if (!__all(pmax <= mrow + 5.0f)) {
      float rmax = fmaxf(pmax, __shfl_xor(pmax, 16));
      rmax = fmaxf(rmax, __shfl_xor(rmax, 32));
      const float mnew = fmaxf(mrow, rmax);
      const float scl = __expf(mrow - mnew);
      mrow = mnew;
      lrow *= scl;
      const int sclI = __float_as_int(scl);
      f32x4 sc4;
#pragma unroll
      for (int i = 0; i < 4; i++)
        sc4[i] = __int_as_float(__builtin_amdgcn_ds_bpermute(((g << 2) + i) << 2, sclI));
#pragma unroll
      for (int f = 0; f < 32; f++) acc[f] *= sc4;
    }
    float p0[4], p1[4];
#pragma unroll
    for (int i = 0; i < 4; i++) { p0[i] = __expf(s0[i] - mrow); p1[i] = __expf(s1[i] - mrow); }
    lrow += (p0[0] + p0[1]) + (p0[2] + p0[3]) + (p1[0] + p1[1]) + (p1[2] + p1[3]);

    // ---- pack P->fp8, redistribute to PV A-fragment (4 bpermutes, register-only) ----
    int w0 = 0, w1 = 0;
    w0 = __builtin_amdgcn_cvt_pk_fp8_f32(p0[0], p0[1], w0, false);
    w0 = __builtin_amdgcn_cvt_pk_fp8_f32(p0[2], p0[3], w0, true);
    w1 = __builtin_amdgcn_cvt_pk_fp8_f32(p1[0], p1[1], w1, false);
    w1 = __builtin_amdgcn_cvt_pk_fp8_f32(p1[2], p1[3], w1, true);
    const int addrA = (((g & 1) << 5) + r16) << 2;   // lane 32*(g&1) + r16
    const int addrB = addrA + 64;                    // +16 lanes
    const int a0 = __builtin_amdgcn_ds_bpermute(addrA, w0);
    const int b0 = __builtin_amdgcn_ds_bpermute(addrB, w0);
    const int a1 = __builtin_amdgcn_ds_bpermute(addrA, w1);
    const int b1 = __builtin_amdgcn_ds_bpermute(addrB, w1);
    const bool lo2 = (g < 2);
    const u32 pA = (u32)(lo2 ? a0 : a1);
    const u32 pB = (u32)(lo2 ? b0 : b1);
    const long pf = (long)(((unsigned long long)pB << 32) | pA);

    // ---- PV: acc += P(fp8) @ V(fp8 in LDS); paired b128 reads feed 2 MFMAs ----
    const u8* vb = &Vs[cur][0] + g * 4096 + r16 * 16;
    __builtin_amdgcn_s_setprio(1);
#pragma unroll
    for (int c2 = 0; c2 < 16; c2++) {
      const i64x2 vv = *(const i64x2*)(vb + c2 * 256);
      acc[2 * c2] = MFMAF8(pf, vv[0], acc[2 * c2]);
      acc[2 * c2 + 1] = MFMAF8(pf, vv[1], acc[2 * c2 + 1]);
    }
    __builtin_amdgcn_s_setprio(0);
    cur = nxt;
    nxt = (nxt == 2) ? 0 : nxt + 1;
  }

  // ---- epilogue: reduce lrow partials, then ctx = acc / lrow * C^-0.5 ----
  float lr = lrow;
  lr += __shfl_xor(lr, 16);
  lr += __shfl_xor(lr, 32);
  const float inv = 0.04419417382415922f / lr;
  const int invI = __float_as_int(inv);
  float fin[4];
#pragma unroll
  for (int i = 0; i < 4; i++)
    fin[i] = __int_as_float(__builtin_amdgcn_ds_bpermute(((g << 2) + i) << 2, invI));
  const size_t ob = (size_t)b * 4096 * 512;
#pragma unroll
  for (int ct = 0; ct < 32; ct++) {
    const int c = (ct << 4) + r16;
#pragma unroll
    for (int i = 0; i < 4; i++) {
      const int n = n0 + w * 16 + (g << 2) + i;
      ctx[ob + (size_t)n * 512 + c] = (bf16)(acc[ct][i] * fin[i]);
    }
  }
}

extern "C" void kernel_launch(void* const* d_in, const int* in_sizes, int n_in,
                              void* d_out, int out_size, void* d_ws, size_t ws_size,
                              hipStream_t stream) {
  const float* feat0 = (const float*)d_in[0];
  const float* feat1 = (const float*)d_in[1];
  const float* Wq = (const float*)d_in[2];
  const float* bq = (const float*)d_in[3];
  const float* Wk = (const float*)d_in[4];
  const float* bk = (const float*)d_in[5];
  const float* Wv = (const float*)d_in[6];
  const float* bv = (const float*)d_in[7];
  const float* Wo = (const float*)d_in[8];
  const float* bo = (const float*)d_in[9];
  float* out = (float*)d_out;

  char* ws = (char*)d_ws;
  bf16* Wqb = (bf16*)(ws);
  bf16* Wkb = (bf16*)(ws + (1 << 19));        // Wkb and Wvb contiguous -> concat [1024][512]
  bf16* Wob = (bf16*)(ws + 3 * (size_t)(1 << 19));
  const size_t TEN = (size_t)8 * 4096 * 512 * 2;  // 33.55 MB per bf16 tensor
  char* p = ws + 4 * (size_t)(1 << 19);
  bf16* Xq  = (bf16*)(p);
  bf16* Xkv = (bf16*)(p + TEN);
  bf16* Qb  = (bf16*)(p + 2 * TEN);
  bf16* Kb  = (bf16*)(p + 3 * TEN);
  bf16* Vtb = (bf16*)(p + 4 * TEN);   // fp8 paired image (16 MB)
  bf16* ctx = Xq;  // Xq dead after Q projection

  convw_k<<<1024, 256, 0, stream>>>(Wq, Wk, Wv, Wo, Wqb);
  tconv_k<<<dim3(128, 16, 16), dim3(32, 8), 0, stream>>>(feat0, feat1, Xq, Xkv);
  gemm_k<0><<<dim3(128, 8), 256, 0, stream>>>(Xq,  Wqb, bq, Qb, nullptr, nullptr);
  gemm_k<4><<<dim3(256, 8), 256, 0, stream>>>(Xkv, Wkb, bk, Kb, (float*)Vtb, bv);
  flash_k<<<dim3(256), dim3(512), 0, stream>>>(Qb, Kb, (const u8*)Vtb, ctx);
  gemm_k<2><<<dim3(128, 8), 256, 0, stream>>>(ctx, Wob, bo, nullptr, out, feat0);
}